// Round 9
// baseline (132.193 us; speedup 1.0000x reference)
//
#include <hip/hip_runtime.h>
#include <hip/hip_bf16.h>
#include <math.h>

#define C_IN 256
#define CC 128
#define NDEPTH 88
#define HW 2816            // 32*88
#define NB 12
#define TILE 32            // hw columns per workgroup (2 strips of 16)
#define NTILES 88          // 2816/32
#define LOG_OFF   ((size_t)8650752)   // 12*256*2816
#define PROB_OFF  ((size_t)11624448)  // + 12*88*2816

typedef __attribute__((ext_vector_type(8))) short bf16x8;
typedef __attribute__((ext_vector_type(4))) float f32x4;

__device__ __forceinline__ unsigned short f2bf(float f) {
    unsigned int u = __float_as_uint(f);
    unsigned int r = (u + 0x7fffu + ((u >> 16) & 1u)) >> 16;
    return (unsigned short)r;
}
__device__ __forceinline__ unsigned int pack2(float a, float b) {
    return (unsigned int)f2bf(a) | ((unsigned int)f2bf(b) << 16);
}
// hardware RNE f32->bf16 (compiler lowers to v_cvt_pk_bf16_f32 pairs)
__device__ __forceinline__ short bfbits(float f) {
    __hip_bfloat16 h = __float2bfloat16(f);
    return *reinterpret_cast<short*>(&h);
}
// barrier that only drains LDS ops (no vmcnt(0) store drain like __syncthreads)
__device__ __forceinline__ void bar_lgkm() {
    asm volatile("s_waitcnt lgkmcnt(0)\n\ts_barrier" ::: "memory");
}
// tanh-approx GELU in sigmoid form
__device__ __forceinline__ float gelu_fast(float v) {
    float u = v * (1.5957691216f + 0.07135481283f * v * v);
    return v / (1.f + __expf(-u));
}

// ---------------- prep: weights -> bf16 in MFMA-fragment-major order ----------------
// w1df: 48 frags  [ks*6 + dt][lane]  (depth rows, zero-padded past 88), ks=0..7
// w1tf: 64 frags  [ks*8 + tt][lane]
// projf: 64 frags [ks*16 + ct][lane]
// each entry = 16 B = 8 bf16: orig[row(m)*K + ks*32 + g*8 .. +7], lane = g*16+m
__global__ void prep_kernel(const float* __restrict__ dnet_w,
                            const float* __restrict__ proj_w,
                            const float* __restrict__ gamma,
                            const float* __restrict__ beta,
                            const float* __restrict__ mean,
                            const float* __restrict__ var,
                            uint4* __restrict__ w1df,
                            uint4* __restrict__ w1tf,
                            uint4* __restrict__ projf,
                            float* __restrict__ scale,
                            float* __restrict__ shift) {
    const int tid = blockIdx.x * blockDim.x + threadIdx.x;
    const int N1 = 48 * 64, N2 = 64 * 64, N3 = 64 * 64;
    for (int e = tid; e < N1 + N2 + N3; e += gridDim.x * blockDim.x) {
        uint4 v = {0u, 0u, 0u, 0u};
        if (e < N1) {
            const int fb = e >> 6, l = e & 63;
            const int ks = fb / 6, dt = fb % 6;
            const int m = l & 15, g = l >> 4;
            const int o = dt * 16 + m;
            if (o < NDEPTH) {
                const float* p = dnet_w + o * 256 + ks * 32 + g * 8;
                v.x = pack2(p[0], p[1]); v.y = pack2(p[2], p[3]);
                v.z = pack2(p[4], p[5]); v.w = pack2(p[6], p[7]);
            }
            w1df[e] = v;
        } else if (e < N1 + N2) {
            const int e2 = e - N1;
            const int fb = e2 >> 6, l = e2 & 63;
            const int ks = fb >> 3, tt = fb & 7;
            const int m = l & 15, g = l >> 4;
            const float* p = dnet_w + (NDEPTH + tt * 16 + m) * 256 + ks * 32 + g * 8;
            v.x = pack2(p[0], p[1]); v.y = pack2(p[2], p[3]);
            v.z = pack2(p[4], p[5]); v.w = pack2(p[6], p[7]);
            w1tf[e2] = v;
        } else {
            const int e3 = e - N1 - N2;
            const int fb = e3 >> 6, l = e3 & 63;
            const int ks = fb >> 4, ct = fb & 15;
            const int m = l & 15, g = l >> 4;
            const float* p = proj_w + (ct * 16 + m) * 128 + ks * 32 + g * 8;
            v.x = pack2(p[0], p[1]); v.y = pack2(p[2], p[3]);
            v.z = pack2(p[4], p[5]); v.w = pack2(p[6], p[7]);
            projf[e3] = v;
        }
    }
    if (tid < 256) {
        float sc = gamma[tid] * rsqrtf(var[tid] + 1e-5f);
        scale[tid] = sc;
        shift[tid] = beta[tid] - mean[tid] * sc;
    }
}

// ---------------- fused main kernel ----------------
// 256 threads = 4 waves = 2 hw-strips x {depth-role, tran-role}
// No x staging: B fragments built from global with per-lane strided loads.
__global__ __launch_bounds__(256, 6)
void fused_kernel(const float* __restrict__ x,
                  const float* __restrict__ dnet_b,
                  const uint4* __restrict__ w1df,
                  const uint4* __restrict__ w1tf,
                  const uint4* __restrict__ projf,
                  const float* __restrict__ scale,
                  const float* __restrict__ shift,
                  float* __restrict__ out) {
    __shared__ __align__(16) unsigned short trs[2][16 * 128];   // 8 KB
    __shared__ float ss[2][16];
    __shared__ float biasd[96];
    __shared__ float biast[128];
    __shared__ float sc_s[256];
    __shared__ float sh_s[256];

    const int bid = blockIdx.x;
    const int n   = bid / NTILES;
    const int hw0 = (bid % NTILES) * TILE;
    const int t     = threadIdx.x;
    const int lane  = t & 63;
    const int wv    = t >> 6;         // 0..3
    const int strip = wv >> 1;        // 0..1
    const int role  = wv & 1;         // 0=depth, 1=tran

    // ---- stage constants into LDS ----
    if (t < 96)       biasd[t] = (t < NDEPTH) ? dnet_b[t] : 0.f;
    else if (t < 224) biast[t - 96] = dnet_b[t - 8];   // dnet_b[88..215]
    sc_s[t] = scale[t];
    sh_s[t] = shift[t];

    const int g = lane >> 4;          // 0..3
    const int m = lane & 15;
    const int hwcol = hw0 + strip * 16 + m;   // global hw of this lane's D column
    const float* xg = x + (size_t)n * C_IN * HW + hwcol;

    // ---- GEMM1 + middle stage, role-split over full K ----
    if (role == 0) {
        // ===== depth =====
        f32x4 accd[6];
        #pragma unroll
        for (int i = 0; i < 6; ++i) accd[i] = (f32x4){0.f, 0.f, 0.f, 0.f};
        const bf16x8* w1dv = (const bf16x8*)w1df;
        #pragma unroll
        for (int ks = 0; ks < 8; ++ks) {
            const int kb = ks * 32 + g * 8;
            bf16x8 b;
            #pragma unroll
            for (int j = 0; j < 8; ++j) b[j] = bfbits(xg[(size_t)(kb + j) * HW]);
            #pragma unroll
            for (int dt = 0; dt < 6; ++dt) {
                bf16x8 a = w1dv[(ks * 6 + dt) * 64 + lane];
                accd[dt] = __builtin_amdgcn_mfma_f32_16x16x32_bf16(a, b, accd[dt], 0, 0, 0);
            }
        }
        // bias -> logits; softmax + expectation (cols = lane&15, reduce ^16,^32)
        #pragma unroll
        for (int dt = 0; dt < 6; ++dt) {
            #pragma unroll
            for (int r = 0; r < 4; ++r)
                accd[dt][r] += biasd[dt * 16 + g * 4 + r];
        }
        float mx = -1e30f;
        #pragma unroll
        for (int dt = 0; dt < 6; ++dt) {
            #pragma unroll
            for (int r = 0; r < 4; ++r) {
                const int o = dt * 16 + g * 4 + r;
                if (o < NDEPTH) mx = fmaxf(mx, accd[dt][r]);
            }
        }
        mx = fmaxf(mx, __shfl_xor(mx, 16));
        mx = fmaxf(mx, __shfl_xor(mx, 32));
        float ev[6][4];
        float sum = 0.f, spn = 0.f;
        #pragma unroll
        for (int dt = 0; dt < 6; ++dt) {
            #pragma unroll
            for (int r = 0; r < 4; ++r) {
                const int o = dt * 16 + g * 4 + r;
                float e = (o < NDEPTH) ? __expf(accd[dt][r] - mx) : 0.f;
                ev[dt][r] = e;
                sum += e;
                spn += e * ((1.f + (float)o * (44.f / 87.f)) * (1.f / 23.f));
            }
        }
        sum += __shfl_xor(sum, 16);
        sum += __shfl_xor(sum, 32);
        spn += __shfl_xor(spn, 16);
        spn += __shfl_xor(spn, 32);
        const float inv = 1.0f / sum;
        if (lane < 16) ss[strip][m] = spn * inv;
        // fire-and-forget stores (lgkm barrier below does NOT drain them)
        float* lg = out + LOG_OFF  + (size_t)n * NDEPTH * HW + hwcol;
        float* pb = out + PROB_OFF + (size_t)n * NDEPTH * HW + hwcol;
        #pragma unroll
        for (int dt = 0; dt < 6; ++dt) {
            #pragma unroll
            for (int r = 0; r < 4; ++r) {
                const int o = dt * 16 + g * 4 + r;
                if (o < NDEPTH) {
                    lg[(size_t)o * HW] = accd[dt][r];
                    pb[(size_t)o * HW] = ev[dt][r] * inv;
                }
            }
        }
    } else {
        // ===== tran =====
        f32x4 acct[8];
        #pragma unroll
        for (int i = 0; i < 8; ++i) acct[i] = (f32x4){0.f, 0.f, 0.f, 0.f};
        const bf16x8* w1tv = (const bf16x8*)w1tf;
        #pragma unroll
        for (int ks = 0; ks < 8; ++ks) {
            const int kb = ks * 32 + g * 8;
            bf16x8 b;
            #pragma unroll
            for (int j = 0; j < 8; ++j) b[j] = bfbits(xg[(size_t)(kb + j) * HW]);
            #pragma unroll
            for (int tt = 0; tt < 8; ++tt) {
                bf16x8 a = w1tv[(ks * 8 + tt) * 64 + lane];
                acct[tt] = __builtin_amdgcn_mfma_f32_16x16x32_bf16(a, b, acct[tt], 0, 0, 0);
            }
        }
        // tran + bias -> trs (bf16, swizzled)
        unsigned short* tw = &trs[strip][0];
        #pragma unroll
        for (int tt = 0; tt < 8; ++tt) {
            const int cb = tt * 16 + g * 4;
            float v0 = acct[tt][0] + biast[cb + 0];
            float v1 = acct[tt][1] + biast[cb + 1];
            float v2 = acct[tt][2] + biast[cb + 2];
            float v3 = acct[tt][3] + biast[cb + 3];
            const int csw = (cb >> 3) ^ (m & 7);
            uint2 pkd;
            pkd.x = pack2(v0, v1);
            pkd.y = pack2(v2, v3);
            *reinterpret_cast<uint2*>(&tw[m * 128 + csw * 8 + (g & 1) * 4]) = pkd;
        }
    }
    bar_lgkm();   // trs + ss visible to both waves of the strip

    // ---- GEMM2: each wave does 8 of 16 output-channel tiles for its strip ----
    const int ctb = role * 8;
    f32x4 acc2[8];
    #pragma unroll
    for (int i = 0; i < 8; ++i) acc2[i] = (f32x4){0.f, 0.f, 0.f, 0.f};
    {
        const bf16x8* pv = (const bf16x8*)projf;
        const unsigned short* tw = &trs[strip][0];
        #pragma unroll
        for (int ks = 0; ks < 4; ++ks) {
            const int k0 = ks * 32;
            const int csw = ((k0 >> 3) + g) ^ (m & 7);
            bf16x8 b = *reinterpret_cast<const bf16x8*>(&tw[m * 128 + csw * 8]);
            #pragma unroll
            for (int ct = 0; ct < 8; ++ct) {
                bf16x8 a = pv[(ks * 16 + ctb + ct) * 64 + lane];
                acc2[ct] = __builtin_amdgcn_mfma_f32_16x16x32_bf16(a, b, acc2[ct], 0, 0, 0);
            }
        }
    }

    // ---- epilogue: BN + GELU + *s, store bev ----
    {
        const float sp = ss[strip][m];
        float* bev = out + (size_t)n * C_IN * HW + hwcol;
        #pragma unroll
        for (int ct = 0; ct < 8; ++ct) {
            #pragma unroll
            for (int r = 0; r < 4; ++r) {
                const int cc = (ctb + ct) * 16 + g * 4 + r;
                float v  = acc2[ct][r] * sc_s[cc] + sh_s[cc];
                bev[(size_t)cc * HW] = gelu_fast(v) * sp;
            }
        }
    }
}

extern "C" void kernel_launch(void* const* d_in, const int* in_sizes, int n_in,
                              void* d_out, int out_size, void* d_ws, size_t ws_size,
                              hipStream_t stream) {
    const float* x      = (const float*)d_in[0];
    const float* dnet_w = (const float*)d_in[1];
    const float* dnet_b = (const float*)d_in[2];
    const float* proj_w = (const float*)d_in[3];
    const float* gamma  = (const float*)d_in[4];
    const float* beta   = (const float*)d_in[5];
    const float* mean   = (const float*)d_in[6];
    const float* var    = (const float*)d_in[7];
    float* out = (float*)d_out;

    char* ws = (char*)d_ws;
    uint4* w1df = (uint4*)ws;                          // 48*64*16  = 49152 B
    uint4* w1tf = (uint4*)(ws + 49152);                // 64*64*16  = 65536 B
    uint4* projf = (uint4*)(ws + 49152 + 65536);       // 64*64*16  = 65536 B
    float* scale = (float*)(ws + 49152 + 65536 + 65536);
    float* shift = scale + 256;

    prep_kernel<<<176, 256, 0, stream>>>(dnet_w, proj_w, gamma, beta, mean, var,
                                         w1df, w1tf, projf, scale, shift);
    fused_kernel<<<NB * NTILES, 256, 0, stream>>>(x, dnet_b, w1df, w1tf, projf,
                                                  scale, shift, out);
}